// Round 11
// baseline (691.115 us; speedup 1.0000x reference)
//
#include <hip/hip_runtime.h>
#include <hip/hip_bf16.h>

#define N_NODES 20000
#define NE      400000

typedef _Float16 half8  __attribute__((ext_vector_type(8)));
typedef _Float16 half4v __attribute__((ext_vector_type(4)));
typedef float    floatx4 __attribute__((ext_vector_type(4)));

// ---------------------------------------------------------------------------
// Fused count + weight-fragment conversion (independent work, one launch).
// ---------------------------------------------------------------------------
__global__ __launch_bounds__(256) void count_wfrag_kernel(
    const int* __restrict__ dst0, int* cnt0,
    const int* __restrict__ dst1, int* cnt1,
    const float* __restrict__ W2a, const float* __restrict__ W2b,
    const float* __restrict__ gWa, const float* __restrict__ gWb,
    const float* __restrict__ c3W,
    const float* __restrict__ W1a, const float* __restrict__ W1b,
    const float* __restrict__ b1a, const float* __restrict__ b1b,
    _Float16* __restrict__ o_w2a, _Float16* __restrict__ o_w2b,
    _Float16* __restrict__ o_gwa, _Float16* __restrict__ o_gwb,
    _Float16* __restrict__ o_c3,
    _Float16* __restrict__ o_uv0, _Float16* __restrict__ o_uv1)
{
    const int NCB = (NE + 255) / 256;   // count blocks
    int b = blockIdx.x;
    int t = threadIdx.x;

    if (b < NCB) {
        int e = b * 256 + t;
        if (e < NE) {
            atomicAdd(&cnt0[dst0[e]], 1);
            atomicAdd(&cnt1[dst1[e]], 1);
        }
        return;
    }
    b -= NCB;

    if (b >= 144) {
        const float* W1 = (b == 145) ? W1b : W1a;
        const float* b1 = (b == 145) ? b1b : b1a;
        _Float16* uv = (b == 145) ? o_uv1 : o_uv0;
        float v0 = W1[3 * 256 + t], v1 = W1[4 * 256 + t], v2 = W1[5 * 256 + t];
        uv[0 * 256 + t] = (_Float16)(W1[0 * 256 + t] + v0);
        uv[1 * 256 + t] = (_Float16)(W1[1 * 256 + t] + v1);
        uv[2 * 256 + t] = (_Float16)(W1[2 * 256 + t] + v2);
        uv[3 * 256 + t] = (_Float16)v0;
        uv[4 * 256 + t] = (_Float16)v1;
        uv[5 * 256 + t] = (_Float16)v2;
        uv[6 * 256 + t] = (_Float16)b1[t];
        return;
    }
    const float* W; _Float16* O; int KST, NC, b0;
    if      (b < 32)  { W = W2a; O = o_w2a; KST = 8;  NC = 256; b0 = 0;   }
    else if (b < 64)  { W = W2b; O = o_w2b; KST = 8;  NC = 256; b0 = 32;  }
    else if (b < 96)  { W = gWa; O = o_gwa; KST = 16; NC = 128; b0 = 64;  }
    else if (b < 128) { W = gWb; O = o_gwb; KST = 16; NC = 128; b0 = 96;  }
    else              { W = c3W; O = o_c3;  KST = 8;  NC = 128; b0 = 128; }

    int tid = (b - b0) * 256 + t;
    int l  = tid & 63;
    int ks = (tid >> 6) % KST;
    int nt = tid / (64 * KST);
    int n  = nt * 16 + (l & 15);
    int kb = ks * 32 + (l >> 4) * 8;
    half8 v;
    #pragma unroll
    for (int j = 0; j < 8; ++j) v[j] = (_Float16)W[(kb + j) * NC + n];
    *(half8*)&O[(size_t)tid * 8] = v;
}

__global__ __launch_bounds__(256) void scan2_kernel(
    const int* __restrict__ cnt0, int* offs0, int* cur0, float* dinv0,
    const int* __restrict__ cnt1, int* offs1, int* cur1, float* dinv1, int n)
{
    const int*  cnt    = blockIdx.x ? cnt1  : cnt0;
    int*        offs   = blockIdx.x ? offs1 : offs0;
    int*        cursor = blockIdx.x ? cur1  : cur0;
    float*      dinv   = blockIdx.x ? dinv1 : dinv0;

    __shared__ int wsum[4];
    __shared__ int carry;
    int t = threadIdx.x, lane = t & 63, w = t >> 6;
    if (t == 0) carry = 0;
    __syncthreads();
    for (int base = 0; base < n; base += 256) {
        int i = base + t;
        int v = (i < n) ? cnt[i] : 0;
        int s = v;
        #pragma unroll
        for (int off = 1; off < 64; off <<= 1) {
            int x = __shfl_up(s, off);
            if (lane >= off) s += x;
        }
        if (lane == 63) wsum[w] = s;
        __syncthreads();
        int add = carry;
        for (int q = 0; q < w; ++q) add += wsum[q];
        if (i < n) {
            int excl = add + s - v;
            offs[i] = excl;
            cursor[i] = excl;
            dinv[i] = rsqrtf(1.0f + (float)v);
        }
        __syncthreads();
        if (t == 0) carry += wsum[0] + wsum[1] + wsum[2] + wsum[3];
        __syncthreads();
    }
    if (t == 0) offs[n] = carry;
}

// writes src-node index directly into the dst-sorted slot (no eid indirection)
__global__ void scatter_kernel(const int* __restrict__ src0, const int* __restrict__ dst0,
                               int* cur0, int* ssrc0,
                               const int* __restrict__ src1, const int* __restrict__ dst1,
                               int* cur1, int* ssrc1) {
    int e = blockIdx.x * blockDim.x + threadIdx.x;
    if (e < NE) {
        int p0 = atomicAdd(&cur0[dst0[e]], 1); ssrc0[p0] = src0[e];
        int p1 = atomicAdd(&cur1[dst1[e]], 1); ssrc1[p1] = src1[e];
    }
}

// ---------------------------------------------------------------------------
// PointNet, both layers in one launch (grid 2500 x 2). Block = 256 thr,
// owns 8 nodes, 32-edge chunks (measured sweet spot: 64-edge regressed in
// r5 via VGPR spill and r9 via LDS-occupancy loss). NEW in r11:
//  - B-fragments (32 x half8 = 128 VGPR/wave, loop-invariant) persisted in
//    registers -> zero per-chunk B L2 traffic (was 3.2 GB/dispatch).
//  - u-slices (12 x half8) and epilogue b2 (4 floats) hoisted to registers;
//    s_u / s_b2 LDS arrays removed (~750 cyc/chunk LDS issue saved).
// Tripwire: FETCH/WRITE balloon => register spill, revert to r10 shape.
// ---------------------------------------------------------------------------
__global__ __launch_bounds__(256) void pointnet_fused_kernel(
    const float* __restrict__ pos0, const float* __restrict__ pos1,
    const int* __restrict__ ssrc0, const int* __restrict__ ssrc1,
    const int* __restrict__ offs0, const int* __restrict__ offs1,
    const _Float16* __restrict__ uv0, const _Float16* __restrict__ uv1,
    const _Float16* __restrict__ Bf0, const _Float16* __restrict__ Bf1,
    const float* __restrict__ b2a, const float* __restrict__ b2b,
    _Float16* __restrict__ out)
{
    const int L = blockIdx.y;
    const float* pos = L ? pos1 : pos0;
    const int* ssrc = L ? ssrc1 : ssrc0;
    const int* offs = L ? offs1 : offs0;
    const _Float16* uv = L ? uv1 : uv0;
    const _Float16* Bf = L ? Bf1 : Bf0;
    const float* b2 = L ? b2b : b2a;
    const int co = L * 256;

    __shared__ float s_ps[2][3][32];
    __shared__ int   s_lid[2][32];
    __shared__ int   s_offs[9];
    __shared__ _Float16 s_c[8][264];             // padded rows
    __shared__ float s_pos[8][3];
    __shared__ _Float16 s_afr[2 * 8 * 64 * 8];   // 16 KB
    __shared__ unsigned int sacc[8][256];        // 8 KB

    const int t = threadIdx.x;
    const int nb = blockIdx.x * 8;
    const int lane = t & 63;
    const int wv = t >> 6;
    const int e    = t & 31;
    const int ksid = t >> 5;

    if (t < 24) s_pos[t / 3][t % 3] = pos[nb * 3 + t];
    if (t >= 32 && t < 41) s_offs[t - 32] = offs[nb + t - 32];
    #pragma unroll
    for (int ln = 0; ln < 8; ++ln) sacc[ln][t] = 0u;

    // ---- loop-invariant register state ----
    // u slices for this thread's 32 channels (phase 1)
    half8 uq[3][4];
    #pragma unroll
    for (int j = 0; j < 3; ++j)
        #pragma unroll
        for (int q = 0; q < 4; ++q)
            uq[j][q] = *(const half8*)&uv[j * 256 + ksid * 32 + q * 8];
    // b2 for this lane's 4 epilogue channels
    float b2r[4];
    #pragma unroll
    for (int q = 0; q < 4; ++q)
        b2r[q] = b2[(wv * 4 + q) * 16 + (lane & 15)];
    // persisted B fragments: wave wv covers nt = wv*4+q
    half8 Breg[8][4];
    #pragma unroll
    for (int ks = 0; ks < 8; ++ks)
        #pragma unroll
        for (int q = 0; q < 4; ++q)
            Breg[ks][q] = *(const half8*)&Bf[(size_t)((((wv * 4 + q) * 8 + ks) * 64 + lane)) * 8];

    __syncthreads();

    const int estart = s_offs[0];
    const int eend   = s_offs[8];

    // per-block c rows: c[ln][ch] = b1[ch] - pos_d . v
    {
        float vx = (float)uv[3 * 256 + t], vy = (float)uv[4 * 256 + t];
        float vz = (float)uv[5 * 256 + t], bb1 = (float)uv[6 * 256 + t];
        #pragma unroll
        for (int ln = 0; ln < 8; ++ln) {
            float c = bb1 - (s_pos[ln][0] * vx + s_pos[ln][1] * vy + s_pos[ln][2] * vz);
            s_c[ln][t] = (_Float16)c;
        }
    }

    // preload first chunk metadata into buffer 0
    if (t < 32) {
        int slot = estart + t;
        int lid = -1;
        float px = 0.f, py = 0.f, pz = 0.f;
        if (slot < eend) {
            int s = ssrc[slot];
            lid = 0;
            #pragma unroll
            for (int k = 1; k < 8; ++k) lid += (slot >= s_offs[k]);
            px = pos[s * 3 + 0]; py = pos[s * 3 + 1]; pz = pos[s * 3 + 2];
        }
        s_lid[0][t] = lid;
        s_ps[0][0][t] = px; s_ps[0][1][t] = py; s_ps[0][2][t] = pz;
    }
    __syncthreads();

    const int mt_e = e >> 4, m_e = e & 15;
    const int rbase = (lane >> 4) * 4;
    const half8 z8 = (half8)(_Float16)0.f;

    int cur = 0;
    for (int ebase = estart; ebase < eend; ebase += 32) {
        // ---- phase 1: hidden = relu(ps.u + c[d]) -> A-frags; 32 ch/thread ----
        {
            _Float16 px = (_Float16)s_ps[cur][0][e];
            _Float16 py = (_Float16)s_ps[cur][1][e];
            _Float16 pz = (_Float16)s_ps[cur][2][e];
            int lid0 = s_lid[cur][e]; lid0 = lid0 >= 0 ? lid0 : 0;
            const _Float16* crow = &s_c[lid0][ksid * 32];
            #pragma unroll
            for (int q = 0; q < 4; ++q) {
                half8 h = *(const half8*)&crow[q * 8];
                h += uq[0][q] * (half8)px;
                h += uq[1][q] * (half8)py;
                h += uq[2][q] * (half8)pz;
                h = __builtin_elementwise_max(h, z8);
                *(half8*)&s_afr[((mt_e * 8 + ksid) * 64 + m_e + 16 * q) * 8] = h;
            }
        }
        __syncthreads();

        // ---- prefetch next chunk metadata (overlaps phase 2) ----
        int nxt = cur ^ 1;
        if (t < 32 && ebase + 32 < eend) {
            int slot = ebase + 32 + t;
            int lid = -1;
            float px = 0.f, py = 0.f, pz = 0.f;
            if (slot < eend) {
                int s = ssrc[slot];
                lid = 0;
                #pragma unroll
                for (int k = 1; k < 8; ++k) lid += (slot >= s_offs[k]);
                px = pos[s * 3 + 0]; py = pos[s * 3 + 1]; pz = pos[s * 3 + 2];
            }
            s_lid[nxt][t] = lid;
            s_ps[nxt][0][t] = px; s_ps[nxt][1][t] = py; s_ps[nxt][2][t] = pz;
        }

        // ---- phase 2: MFMA (32 edges x 64 ch per wave), B from registers ----
        floatx4 acc[2][4];
        #pragma unroll
        for (int mt = 0; mt < 2; ++mt)
            #pragma unroll
            for (int q = 0; q < 4; ++q) acc[mt][q] = (floatx4){0.f, 0.f, 0.f, 0.f};

        #pragma unroll
        for (int ks = 0; ks < 8; ++ks) {
            half8 aa0 = *(const half8*)&s_afr[((0 * 8 + ks) * 64 + lane) * 8];
            half8 aa1 = *(const half8*)&s_afr[((1 * 8 + ks) * 64 + lane) * 8];
            #pragma unroll
            for (int q = 0; q < 4; ++q) {
                acc[0][q] = __builtin_amdgcn_mfma_f32_16x16x32_f16(aa0, Breg[ks][q], acc[0][q], 0, 0, 0);
                acc[1][q] = __builtin_amdgcn_mfma_f32_16x16x32_f16(aa1, Breg[ks][q], acc[1][q], 0, 0, 0);
            }
        }

        // ---- epilogue: segmented max, sorted-lid fast path ----
        #pragma unroll
        for (int mt = 0; mt < 2; ++mt) {
            int4 l4 = *(const int4*)&s_lid[cur][mt * 16 + rbase];
            #pragma unroll
            for (int q = 0; q < 4; ++q) {
                int ch = (wv * 4 + q) * 16 + (lane & 15);
                float bb = b2r[q];
                float v0 = acc[mt][q][0] + bb;
                float v1 = acc[mt][q][1] + bb;
                float v2 = acc[mt][q][2] + bb;
                float v3 = acc[mt][q][3] + bb;
                if (l4.x == l4.w) {
                    float m = fmaxf(fmaxf(v0, v1), fmaxf(v2, v3));
                    if (l4.x >= 0 && m > 0.f) atomicMax(&sacc[l4.x][ch], __float_as_uint(m));
                } else {
                    if (l4.x >= 0 && v0 > 0.f) atomicMax(&sacc[l4.x][ch], __float_as_uint(v0));
                    if (l4.y >= 0 && v1 > 0.f) atomicMax(&sacc[l4.y][ch], __float_as_uint(v1));
                    if (l4.z >= 0 && v2 > 0.f) atomicMax(&sacc[l4.z][ch], __float_as_uint(v2));
                    if (l4.w >= 0 && v3 > 0.f) atomicMax(&sacc[l4.w][ch], __float_as_uint(v3));
                }
            }
        }
        __syncthreads();
        cur = nxt;
    }

    // ---- final store (fp16 row-major) ----
    #pragma unroll
    for (int ln = 0; ln < 8; ++ln)
        out[(size_t)(nb + ln) * 512 + co + t] = (_Float16)__uint_as_float(sacc[ln][t]);
}

// ---------------------------------------------------------------------------
// MFMA GEMM (pair-fused via grid.z): C = (A@Bf) * scale[row] -> fp16
// ---------------------------------------------------------------------------
template <int KSTEPS>
__global__ __launch_bounds__(256) void gemm_mfma2_kernel(
    const _Float16* __restrict__ A,
    const _Float16* __restrict__ Bfa, const _Float16* __restrict__ Bfb,
    const float* __restrict__ sca, const float* __restrict__ scb,
    _Float16* __restrict__ Ca, _Float16* __restrict__ Cb)
{
    const _Float16* Bf = blockIdx.z ? Bfb : Bfa;
    const float* scale = blockIdx.z ? scb : sca;
    _Float16* C = blockIdx.z ? Cb : Ca;

    const int t = threadIdx.x;
    const int lane = t & 63;
    const int wv = t >> 6;
    const int mb = blockIdx.x * 32;
    const int nt = blockIdx.y * 4 + wv;
    const int K = KSTEPS * 32;

    const size_t arow0 = (size_t)(mb + (lane & 15)) * K + (lane >> 4) * 8;
    const size_t arow1 = arow0 + (size_t)16 * K;

    floatx4 acc0 = (floatx4){0.f, 0.f, 0.f, 0.f};
    floatx4 acc1 = (floatx4){0.f, 0.f, 0.f, 0.f};

    #pragma unroll
    for (int ks = 0; ks < KSTEPS; ++ks) {
        half8 a0 = *(const half8*)&A[arow0 + ks * 32];
        half8 a1 = *(const half8*)&A[arow1 + ks * 32];
        half8 b  = *(const half8*)&Bf[(size_t)((nt * KSTEPS + ks) * 64 + lane) * 8];
        acc0 = __builtin_amdgcn_mfma_f32_16x16x32_f16(a0, b, acc0, 0, 0, 0);
        acc1 = __builtin_amdgcn_mfma_f32_16x16x32_f16(a1, b, acc1, 0, 0, 0);
    }

    const int col = nt * 16 + (lane & 15);
    const int rb  = (lane >> 4) * 4;
    #pragma unroll
    for (int r = 0; r < 4; ++r) {
        int r0 = mb + rb + r, r1 = mb + 16 + rb + r;
        C[(size_t)r0 * 128 + col] = (_Float16)(acc0[r] * scale[r0]);
        C[(size_t)r1 * 128 + col] = (_Float16)(acc1[r] * scale[r1]);
    }
}

// ---------------------------------------------------------------------------
// GCN gather (pair-fused via grid.y), wave-per-node, 4 edges/iteration:
// quarter-wave per edge, 8 ch/lane (half8 16B loads). xwn pre-normalized.
// ---------------------------------------------------------------------------
__global__ __launch_bounds__(256) void gcn_gather2_kernel(
    const int* __restrict__ ssrc0, const int* __restrict__ ssrc1,
    const int* __restrict__ offs0, const int* __restrict__ offs1,
    const float* __restrict__ dinv0, const float* __restrict__ dinv1,
    const _Float16* __restrict__ xwn0, const _Float16* __restrict__ xwn1,
    const float* __restrict__ b0, const float* __restrict__ b1v,
    _Float16* __restrict__ h2)
{
    const int L = blockIdx.y;
    const int* ssrc = L ? ssrc1 : ssrc0;
    const int* offs = L ? offs1 : offs0;
    const float* dinv = L ? dinv1 : dinv0;
    const _Float16* xwn = L ? xwn1 : xwn0;
    const float* b = L ? b1v : b0;
    const int co = L * 128;

    const int t = threadIdx.x;
    const int lane = t & 63;
    const int qg = lane >> 4;
    const int lq = lane & 15;
    const int i = blockIdx.x * 4 + (t >> 6);
    const int e0 = offs[i], e1 = offs[i + 1];
    const float di = dinv[i];

    float ax[8];
    {
        half8 xi = *(const half8*)&xwn[(size_t)i * 128 + lq * 8];
        #pragma unroll
        for (int k = 0; k < 8; ++k) ax[k] = (qg == 0) ? (float)xi[k] : 0.f;
    }

    for (int base = e0; base < e1; base += 64) {
        int k = base + lane;
        int s = 0;
        if (k < e1) s = ssrc[k];
        int m = min(64, e1 - base);
        for (int j = 0; j < m; j += 4) {
            int idx = j + qg;
            int sj = __shfl(s, idx);
            if (idx < m) {
                half8 v = *(const half8*)&xwn[(size_t)sj * 128 + lq * 8];
                #pragma unroll
                for (int k2 = 0; k2 < 8; ++k2) ax[k2] += (float)v[k2];
            }
        }
    }

    #pragma unroll
    for (int k = 0; k < 8; ++k) {
        ax[k] += __shfl(ax[k], lane ^ 16);
        ax[k] += __shfl(ax[k], lane ^ 32);
    }

    if (qg == 0) {
        half8 o;
        #pragma unroll
        for (int k = 0; k < 8; ++k)
            o[k] = (_Float16)fmaxf(ax[k] * di + b[lq * 8 + k], 0.f);
        *(half8*)&h2[(size_t)i * 256 + co + lq * 8] = o;
    }
}

// ---------------------------------------------------------------------------
// c3 GEMM fused with classifier: z = relu(h2 @ c3W + c3b) in-register,
// reduced against clsW -> 3 atomicAdds per block.
// ---------------------------------------------------------------------------
__global__ __launch_bounds__(256) void gemm_c3cls_kernel(
    const _Float16* __restrict__ A, const _Float16* __restrict__ Bf,
    const float* __restrict__ bias,
    const float* __restrict__ clsW, const float* __restrict__ clsb,
    float* __restrict__ out)
{
    const int KSTEPS = 8;
    const int t = threadIdx.x;
    const int lane = t & 63;
    const int wv = t >> 6;
    const int mb = blockIdx.x * 32;
    const int nt = blockIdx.y * 4 + wv;
    const int K = 256;

    const size_t arow0 = (size_t)(mb + (lane & 15)) * K + (lane >> 4) * 8;
    const size_t arow1 = arow0 + (size_t)16 * K;

    floatx4 acc0 = (floatx4){0.f, 0.f, 0.f, 0.f};
    floatx4 acc1 = (floatx4){0.f, 0.f, 0.f, 0.f};

    #pragma unroll
    for (int ks = 0; ks < KSTEPS; ++ks) {
        half8 a0 = *(const half8*)&A[arow0 + ks * 32];
        half8 a1 = *(const half8*)&A[arow1 + ks * 32];
        half8 b  = *(const half8*)&Bf[(size_t)((nt * KSTEPS + ks) * 64 + lane) * 8];
        acc0 = __builtin_amdgcn_mfma_f32_16x16x32_f16(a0, b, acc0, 0, 0, 0);
        acc1 = __builtin_amdgcn_mfma_f32_16x16x32_f16(a1, b, acc1, 0, 0, 0);
    }

    const int col = nt * 16 + (lane & 15);
    const int rb  = (lane >> 4) * 4;
    const float bb = bias[col];
    float a0 = 0.f, a1 = 0.f, a2 = 0.f;
    #pragma unroll
    for (int r = 0; r < 4; ++r) {
        int r0 = mb + rb + r, r1 = mb + 16 + rb + r;
        float z0 = fmaxf(acc0[r] + bb, 0.f);
        float z1 = fmaxf(acc1[r] + bb, 0.f);
        size_t f0 = ((size_t)r0 * 128 + col) * 3;
        size_t f1 = ((size_t)r1 * 128 + col) * 3;
        a0 += z0 * clsW[f0 + 0] + z1 * clsW[f1 + 0];
        a1 += z0 * clsW[f0 + 1] + z1 * clsW[f1 + 1];
        a2 += z0 * clsW[f0 + 2] + z1 * clsW[f1 + 2];
    }

    #pragma unroll
    for (int off = 32; off > 0; off >>= 1) {
        a0 += __shfl_down(a0, off);
        a1 += __shfl_down(a1, off);
        a2 += __shfl_down(a2, off);
    }
    __shared__ float sred[12];
    if ((t & 63) == 0) { sred[wv * 3] = a0; sred[wv * 3 + 1] = a1; sred[wv * 3 + 2] = a2; }
    __syncthreads();
    if (t == 0) {
        float r0 = 0.f, r1 = 0.f, r2 = 0.f;
        #pragma unroll
        for (int q = 0; q < 4; ++q) { r0 += sred[q * 3]; r1 += sred[q * 3 + 1]; r2 += sred[q * 3 + 2]; }
        atomicAdd(&out[0], r0); atomicAdd(&out[1], r1); atomicAdd(&out[2], r2);
    }
    if (blockIdx.x == 0 && blockIdx.y == 0 && t < 3) atomicAdd(&out[t], clsb[t]);
}

// ---------------------------------------------------------------------------
extern "C" void kernel_launch(void* const* d_in, const int* in_sizes, int n_in,
                              void* d_out, int out_size, void* d_ws, size_t ws_size,
                              hipStream_t stream) {
    const float* pos0 = (const float*)d_in[0];
    const float* pos1 = (const float*)d_in[1];
    const int*   ei0  = (const int*)d_in[2];
    const int*   ei1  = (const int*)d_in[3];
    const float* p0W1 = (const float*)d_in[6];
    const float* p0b1 = (const float*)d_in[7];
    const float* p0W2 = (const float*)d_in[8];
    const float* p0b2 = (const float*)d_in[9];
    const float* p1W1 = (const float*)d_in[10];
    const float* p1b1 = (const float*)d_in[11];
    const float* p1W2 = (const float*)d_in[12];
    const float* p1b2 = (const float*)d_in[13];
    const float* g0W  = (const float*)d_in[14];
    const float* g0b  = (const float*)d_in[15];
    const float* g1W  = (const float*)d_in[16];
    const float* g1b  = (const float*)d_in[17];
    const float* c3W  = (const float*)d_in[18];
    const float* c3b  = (const float*)d_in[19];
    const float* clsW = (const float*)d_in[20];
    const float* clsb = (const float*)d_in[21];

    const int* s0 = ei0;       const int* d0 = ei0 + NE;
    const int* s1 = ei1;       const int* d1 = ei1 + NE;

    float* ws = (float*)d_ws;
    _Float16* h   = (_Float16*)ws;               // [N,512] fp16
    _Float16* xw0 = (_Float16*)(ws + 5120000);   // [N,128] fp16 (pre-normalized)
    _Float16* xw1 = (_Float16*)(ws + 7680000);
    _Float16* h2  = (_Float16*)(ws + 10240000);  // [N,256] fp16
    int*   cnt0  = (int*)(ws + 15360000);        // [N]
    int*   cnt1  = (int*)(ws + 15380000);
    int*   cur0  = (int*)(ws + 15400000);
    int*   cur1  = (int*)(ws + 15420000);
    int*   offs0 = (int*)(ws + 15440000);        // [N+1]
    int*   offs1 = (int*)(ws + 15460004);        // [N+1]
    int*   ssrc0 = (int*)(ws + 15480008);        // [E] src payload, dst-sorted
    int*   ssrc1 = (int*)(ws + 15880008);
    float* dinv0 = ws + 16280008;                // [N]
    float* dinv1 = ws + 16300008;
    _Float16* w2f0 = (_Float16*)(ws + 16320008); // 65536 halfs
    _Float16* w2f1 = (_Float16*)(ws + 16352776);
    _Float16* gwf0 = (_Float16*)(ws + 16385544); // 65536 halfs
    _Float16* gwf1 = (_Float16*)(ws + 16418312);
    _Float16* c3f  = (_Float16*)(ws + 16451080); // 32768 halfs
    _Float16* uvb0 = (_Float16*)(ws + 16467464); // 1792 halfs each
    _Float16* uvb1 = (_Float16*)(ws + 16468488);

    hipMemsetAsync(cnt0, 0, (size_t)2 * N_NODES * sizeof(int), stream);
    hipMemsetAsync(d_out, 0, 3 * sizeof(float), stream);

    // fused histogram + weight fragment / uvb conversions
    const int NCB = (NE + 255) / 256;
    count_wfrag_kernel<<<NCB + 146, 256, 0, stream>>>(
        d0, cnt0, d1, cnt1, p0W2, p1W2, g0W, g1W, c3W,
        p0W1, p1W1, p0b1, p1b1,
        w2f0, w2f1, gwf0, gwf1, c3f, uvb0, uvb1);
    scan2_kernel<<<2, 256, 0, stream>>>(cnt0, offs0, cur0, dinv0,
                                        cnt1, offs1, cur1, dinv1, N_NODES);
    scatter_kernel<<<(NE + 255) / 256, 256, 0, stream>>>(
        s0, d0, cur0, ssrc0, s1, d1, cur1, ssrc1);

    // PointNet, both layers in one dispatch -> h [N,512] fp16
    pointnet_fused_kernel<<<dim3(N_NODES / 8, 2), 256, 0, stream>>>(
        pos0, pos1, ssrc0, ssrc1, offs0, offs1,
        uvb0, uvb1, w2f0, w2f1, p0b2, p1b2, h);

    // xwn pair = (h @ gW) * dinv[row] (fp16 MFMA, K=512) -> fp16
    gemm_mfma2_kernel<16><<<dim3(N_NODES / 32, 2, 2), 256, 0, stream>>>(
        h, gwf0, gwf1, dinv0, dinv1, xw0, xw1);

    // fused GCN aggregation pair (pure segment-sum, 4 edges/iter) -> h2 fp16
    gcn_gather2_kernel<<<dim3(N_NODES / 4, 2), 256, 0, stream>>>(
        ssrc0, ssrc1, offs0, offs1, dinv0, dinv1, xw0, xw1, g0b, g1b, h2);

    // z = relu(h2 @ c3W + c3b) fused with classifier -> out[3]
    gemm_c3cls_kernel<<<dim3(N_NODES / 32, 2), 256, 0, stream>>>(
        h2, c3f, c3b, clsW, clsb, (float*)d_out);
}

// Round 13
// 511.139 us; speedup vs baseline: 1.3521x; 1.3521x over previous
//
#include <hip/hip_runtime.h>
#include <hip/hip_bf16.h>

#define N_NODES 20000
#define NE      400000
#define NMB     (N_NODES / 32)   // 625 c3cls blocks

typedef _Float16 half8  __attribute__((ext_vector_type(8)));
typedef _Float16 half4v __attribute__((ext_vector_type(4)));
typedef float    floatx4 __attribute__((ext_vector_type(4)));

// ---------------------------------------------------------------------------
// Fused count + weight-fragment conversion (independent work, one launch).
// ---------------------------------------------------------------------------
__global__ __launch_bounds__(256) void count_wfrag_kernel(
    const int* __restrict__ dst0, int* cnt0,
    const int* __restrict__ dst1, int* cnt1,
    const float* __restrict__ W2a, const float* __restrict__ W2b,
    const float* __restrict__ gWa, const float* __restrict__ gWb,
    const float* __restrict__ c3W,
    const float* __restrict__ W1a, const float* __restrict__ W1b,
    const float* __restrict__ b1a, const float* __restrict__ b1b,
    _Float16* __restrict__ o_w2a, _Float16* __restrict__ o_w2b,
    _Float16* __restrict__ o_gwa, _Float16* __restrict__ o_gwb,
    _Float16* __restrict__ o_c3,
    _Float16* __restrict__ o_uv0, _Float16* __restrict__ o_uv1)
{
    const int NCB = (NE + 255) / 256;   // count blocks
    int b = blockIdx.x;
    int t = threadIdx.x;

    if (b < NCB) {
        int e = b * 256 + t;
        if (e < NE) {
            atomicAdd(&cnt0[dst0[e]], 1);
            atomicAdd(&cnt1[dst1[e]], 1);
        }
        return;
    }
    b -= NCB;

    if (b >= 144) {
        const float* W1 = (b == 145) ? W1b : W1a;
        const float* b1 = (b == 145) ? b1b : b1a;
        _Float16* uv = (b == 145) ? o_uv1 : o_uv0;
        float v0 = W1[3 * 256 + t], v1 = W1[4 * 256 + t], v2 = W1[5 * 256 + t];
        uv[0 * 256 + t] = (_Float16)(W1[0 * 256 + t] + v0);
        uv[1 * 256 + t] = (_Float16)(W1[1 * 256 + t] + v1);
        uv[2 * 256 + t] = (_Float16)(W1[2 * 256 + t] + v2);
        uv[3 * 256 + t] = (_Float16)v0;
        uv[4 * 256 + t] = (_Float16)v1;
        uv[5 * 256 + t] = (_Float16)v2;
        uv[6 * 256 + t] = (_Float16)b1[t];
        return;
    }
    const float* W; _Float16* O; int KST, NC, b0;
    if      (b < 32)  { W = W2a; O = o_w2a; KST = 8;  NC = 256; b0 = 0;   }
    else if (b < 64)  { W = W2b; O = o_w2b; KST = 8;  NC = 256; b0 = 32;  }
    else if (b < 96)  { W = gWa; O = o_gwa; KST = 16; NC = 128; b0 = 64;  }
    else if (b < 128) { W = gWb; O = o_gwb; KST = 16; NC = 128; b0 = 96;  }
    else              { W = c3W; O = o_c3;  KST = 8;  NC = 128; b0 = 128; }

    int tid = (b - b0) * 256 + t;
    int l  = tid & 63;
    int ks = (tid >> 6) % KST;
    int nt = tid / (64 * KST);
    int n  = nt * 16 + (l & 15);
    int kb = ks * 32 + (l >> 4) * 8;
    half8 v;
    #pragma unroll
    for (int j = 0; j < 8; ++j) v[j] = (_Float16)W[(kb + j) * NC + n];
    *(half8*)&O[(size_t)tid * 8] = v;
}

__global__ __launch_bounds__(256) void scan2_kernel(
    const int* __restrict__ cnt0, int* offs0, int* cur0, float* dinv0,
    const int* __restrict__ cnt1, int* offs1, int* cur1, float* dinv1, int n)
{
    const int*  cnt    = blockIdx.x ? cnt1  : cnt0;
    int*        offs   = blockIdx.x ? offs1 : offs0;
    int*        cursor = blockIdx.x ? cur1  : cur0;
    float*      dinv   = blockIdx.x ? dinv1 : dinv0;

    __shared__ int wsum[4];
    __shared__ int carry;
    int t = threadIdx.x, lane = t & 63, w = t >> 6;
    if (t == 0) carry = 0;
    __syncthreads();
    for (int base = 0; base < n; base += 256) {
        int i = base + t;
        int v = (i < n) ? cnt[i] : 0;
        int s = v;
        #pragma unroll
        for (int off = 1; off < 64; off <<= 1) {
            int x = __shfl_up(s, off);
            if (lane >= off) s += x;
        }
        if (lane == 63) wsum[w] = s;
        __syncthreads();
        int add = carry;
        for (int q = 0; q < w; ++q) add += wsum[q];
        if (i < n) {
            int excl = add + s - v;
            offs[i] = excl;
            cursor[i] = excl;
            dinv[i] = rsqrtf(1.0f + (float)v);
        }
        __syncthreads();
        if (t == 0) carry += wsum[0] + wsum[1] + wsum[2] + wsum[3];
        __syncthreads();
    }
    if (t == 0) offs[n] = carry;
}

// writes src-node index directly into the dst-sorted slot (no eid indirection)
__global__ void scatter_kernel(const int* __restrict__ src0, const int* __restrict__ dst0,
                               int* cur0, int* ssrc0,
                               const int* __restrict__ src1, const int* __restrict__ dst1,
                               int* cur1, int* ssrc1) {
    int e = blockIdx.x * blockDim.x + threadIdx.x;
    if (e < NE) {
        int p0 = atomicAdd(&cur0[dst0[e]], 1); ssrc0[p0] = src0[e];
        int p1 = atomicAdd(&cur1[dst1[e]], 1); ssrc1[p1] = src1[e];
    }
}

// ---------------------------------------------------------------------------
// PointNet, both layers in one launch (grid 2500 x 2). Block = 256 thr,
// owns 8 nodes, 32-edge chunks. LOCAL-OPTIMUM NOTE: this exact resource
// shape (120 VGPR / 33 KB LDS / 4-5 blocks/CU) is measured-best (r10,
// 206 us). Three escape attempts all regressed by losing occupancy:
// r5 spill, r9 LDS 49 KB, r11 B-frag registers. Do not grow VGPR or LDS.
// ---------------------------------------------------------------------------
__global__ __launch_bounds__(256) void pointnet_fused_kernel(
    const float* __restrict__ pos0, const float* __restrict__ pos1,
    const int* __restrict__ ssrc0, const int* __restrict__ ssrc1,
    const int* __restrict__ offs0, const int* __restrict__ offs1,
    const _Float16* __restrict__ uv0, const _Float16* __restrict__ uv1,
    const _Float16* __restrict__ Bf0, const _Float16* __restrict__ Bf1,
    const float* __restrict__ b2a, const float* __restrict__ b2b,
    _Float16* __restrict__ out)
{
    const int L = blockIdx.y;
    const float* pos = L ? pos1 : pos0;
    const int* ssrc = L ? ssrc1 : ssrc0;
    const int* offs = L ? offs1 : offs0;
    const _Float16* uv = L ? uv1 : uv0;
    const _Float16* Bf = L ? Bf1 : Bf0;
    const float* b2 = L ? b2b : b2a;
    const int co = L * 256;

    __shared__ float s_ps[2][3][32];
    __shared__ int   s_lid[2][32];
    __shared__ int   s_offs[9];
    __shared__ _Float16 s_u[3][256];
    __shared__ _Float16 s_c[8][264];             // padded rows
    __shared__ float s_b2[256];
    __shared__ float s_pos[8][3];
    __shared__ _Float16 s_afr[2 * 8 * 64 * 8];   // 16 KB
    __shared__ unsigned int sacc[8][256];        // 8 KB

    const int t = threadIdx.x;
    const int nb = blockIdx.x * 8;
    const int lane = t & 63;
    const int wv = t >> 6;

    #pragma unroll
    for (int j = 0; j < 3; ++j) s_u[j][t] = uv[j * 256 + t];
    s_b2[t] = b2[t];
    if (t < 24) s_pos[t / 3][t % 3] = pos[nb * 3 + t];
    if (t >= 32 && t < 41) s_offs[t - 32] = offs[nb + t - 32];
    #pragma unroll
    for (int ln = 0; ln < 8; ++ln) sacc[ln][t] = 0u;
    __syncthreads();

    const int estart = s_offs[0];
    const int eend   = s_offs[8];

    // per-block c rows: c[ln][ch] = b1[ch] - pos_d . v
    {
        float vx = (float)uv[3 * 256 + t], vy = (float)uv[4 * 256 + t];
        float vz = (float)uv[5 * 256 + t], bb1 = (float)uv[6 * 256 + t];
        #pragma unroll
        for (int ln = 0; ln < 8; ++ln) {
            float c = bb1 - (s_pos[ln][0] * vx + s_pos[ln][1] * vy + s_pos[ln][2] * vz);
            s_c[ln][t] = (_Float16)c;
        }
    }

    // preload first chunk metadata into buffer 0
    if (t < 32) {
        int slot = estart + t;
        int lid = -1;
        float px = 0.f, py = 0.f, pz = 0.f;
        if (slot < eend) {
            int s = ssrc[slot];
            lid = 0;
            #pragma unroll
            for (int k = 1; k < 8; ++k) lid += (slot >= s_offs[k]);
            px = pos[s * 3 + 0]; py = pos[s * 3 + 1]; pz = pos[s * 3 + 2];
        }
        s_lid[0][t] = lid;
        s_ps[0][0][t] = px; s_ps[0][1][t] = py; s_ps[0][2][t] = pz;
    }
    __syncthreads();

    const int e    = t & 31;
    const int ksid = t >> 5;
    const int mt_e = e >> 4, m_e = e & 15;
    const int rbase = (lane >> 4) * 4;
    const half8 z8 = (half8)(_Float16)0.f;

    int cur = 0;
    for (int ebase = estart; ebase < eend; ebase += 32) {
        // ---- phase 1: hidden = relu(ps.u + c[d]) -> A-frags; 32 ch/thread ----
        {
            _Float16 px = (_Float16)s_ps[cur][0][e];
            _Float16 py = (_Float16)s_ps[cur][1][e];
            _Float16 pz = (_Float16)s_ps[cur][2][e];
            int lid0 = s_lid[cur][e]; lid0 = lid0 >= 0 ? lid0 : 0;
            const _Float16* crow = &s_c[lid0][ksid * 32];
            const int ub = ksid * 32;
            #pragma unroll
            for (int q = 0; q < 4; ++q) {
                half8 h = *(const half8*)&crow[q * 8];
                h += (*(const half8*)&s_u[0][ub + q * 8]) * (half8)px;
                h += (*(const half8*)&s_u[1][ub + q * 8]) * (half8)py;
                h += (*(const half8*)&s_u[2][ub + q * 8]) * (half8)pz;
                h = __builtin_elementwise_max(h, z8);
                *(half8*)&s_afr[((mt_e * 8 + ksid) * 64 + m_e + 16 * q) * 8] = h;
            }
        }
        __syncthreads();

        // ---- prefetch next chunk metadata (overlaps phase 2) ----
        int nxt = cur ^ 1;
        if (t < 32 && ebase + 32 < eend) {
            int slot = ebase + 32 + t;
            int lid = -1;
            float px = 0.f, py = 0.f, pz = 0.f;
            if (slot < eend) {
                int s = ssrc[slot];
                lid = 0;
                #pragma unroll
                for (int k = 1; k < 8; ++k) lid += (slot >= s_offs[k]);
                px = pos[s * 3 + 0]; py = pos[s * 3 + 1]; pz = pos[s * 3 + 2];
            }
            s_lid[nxt][t] = lid;
            s_ps[nxt][0][t] = px; s_ps[nxt][1][t] = py; s_ps[nxt][2][t] = pz;
        }

        // ---- phase 2: MFMA (32 edges x 64 ch per wave) ----
        floatx4 acc[2][4];
        #pragma unroll
        for (int mt = 0; mt < 2; ++mt)
            #pragma unroll
            for (int q = 0; q < 4; ++q) acc[mt][q] = (floatx4){0.f, 0.f, 0.f, 0.f};

        #pragma unroll
        for (int ks = 0; ks < 8; ++ks) {
            half8 aa0 = *(const half8*)&s_afr[((0 * 8 + ks) * 64 + lane) * 8];
            half8 aa1 = *(const half8*)&s_afr[((1 * 8 + ks) * 64 + lane) * 8];
            #pragma unroll
            for (int q = 0; q < 4; ++q) {
                int nt = wv * 4 + q;
                half8 b = *(const half8*)&Bf[(size_t)((nt * 8 + ks) * 64 + lane) * 8];
                acc[0][q] = __builtin_amdgcn_mfma_f32_16x16x32_f16(aa0, b, acc[0][q], 0, 0, 0);
                acc[1][q] = __builtin_amdgcn_mfma_f32_16x16x32_f16(aa1, b, acc[1][q], 0, 0, 0);
            }
        }

        // ---- epilogue: segmented max, sorted-lid fast path ----
        #pragma unroll
        for (int mt = 0; mt < 2; ++mt) {
            int4 l4 = *(const int4*)&s_lid[cur][mt * 16 + rbase];
            #pragma unroll
            for (int q = 0; q < 4; ++q) {
                int ch = (wv * 4 + q) * 16 + (lane & 15);
                float bb = s_b2[ch];
                float v0 = acc[mt][q][0] + bb;
                float v1 = acc[mt][q][1] + bb;
                float v2 = acc[mt][q][2] + bb;
                float v3 = acc[mt][q][3] + bb;
                if (l4.x == l4.w) {
                    float m = fmaxf(fmaxf(v0, v1), fmaxf(v2, v3));
                    if (l4.x >= 0 && m > 0.f) atomicMax(&sacc[l4.x][ch], __float_as_uint(m));
                } else {
                    if (l4.x >= 0 && v0 > 0.f) atomicMax(&sacc[l4.x][ch], __float_as_uint(v0));
                    if (l4.y >= 0 && v1 > 0.f) atomicMax(&sacc[l4.y][ch], __float_as_uint(v1));
                    if (l4.z >= 0 && v2 > 0.f) atomicMax(&sacc[l4.z][ch], __float_as_uint(v2));
                    if (l4.w >= 0 && v3 > 0.f) atomicMax(&sacc[l4.w][ch], __float_as_uint(v3));
                }
            }
        }
        __syncthreads();
        cur = nxt;
    }

    // ---- final store (fp16 row-major) ----
    #pragma unroll
    for (int ln = 0; ln < 8; ++ln)
        out[(size_t)(nb + ln) * 512 + co + t] = (_Float16)__uint_as_float(sacc[ln][t]);
}

// ---------------------------------------------------------------------------
// MFMA GEMM (pair-fused via grid.z): C = (A@Bf) * scale[row] -> fp16
// Widened: each block covers all 128 cols (2 n-tiles per wave), halving
// A re-reads vs the 64-col version. grid (M/32, 1, 2).
// ---------------------------------------------------------------------------
template <int KSTEPS>
__global__ __launch_bounds__(256) void gemm_mfma2_kernel(
    const _Float16* __restrict__ A,
    const _Float16* __restrict__ Bfa, const _Float16* __restrict__ Bfb,
    const float* __restrict__ sca, const float* __restrict__ scb,
    _Float16* __restrict__ Ca, _Float16* __restrict__ Cb)
{
    const _Float16* Bf = blockIdx.z ? Bfb : Bfa;
    const float* scale = blockIdx.z ? scb : sca;
    _Float16* C = blockIdx.z ? Cb : Ca;

    const int t = threadIdx.x;
    const int lane = t & 63;
    const int wv = t >> 6;
    const int mb = blockIdx.x * 32;
    const int ntb = wv * 2;
    const int K = KSTEPS * 32;

    const size_t arow0 = (size_t)(mb + (lane & 15)) * K + (lane >> 4) * 8;
    const size_t arow1 = arow0 + (size_t)16 * K;

    floatx4 acc[2][2];
    #pragma unroll
    for (int n = 0; n < 2; ++n)
        #pragma unroll
        for (int r = 0; r < 2; ++r) acc[n][r] = (floatx4){0.f, 0.f, 0.f, 0.f};

    #pragma unroll
    for (int ks = 0; ks < KSTEPS; ++ks) {
        half8 a0 = *(const half8*)&A[arow0 + ks * 32];
        half8 a1 = *(const half8*)&A[arow1 + ks * 32];
        half8 b0 = *(const half8*)&Bf[(size_t)(((ntb + 0) * KSTEPS + ks) * 64 + lane) * 8];
        half8 b1 = *(const half8*)&Bf[(size_t)(((ntb + 1) * KSTEPS + ks) * 64 + lane) * 8];
        acc[0][0] = __builtin_amdgcn_mfma_f32_16x16x32_f16(a0, b0, acc[0][0], 0, 0, 0);
        acc[0][1] = __builtin_amdgcn_mfma_f32_16x16x32_f16(a1, b0, acc[0][1], 0, 0, 0);
        acc[1][0] = __builtin_amdgcn_mfma_f32_16x16x32_f16(a0, b1, acc[1][0], 0, 0, 0);
        acc[1][1] = __builtin_amdgcn_mfma_f32_16x16x32_f16(a1, b1, acc[1][1], 0, 0, 0);
    }

    const int rb = (lane >> 4) * 4;
    #pragma unroll
    for (int n = 0; n < 2; ++n) {
        const int col = (ntb + n) * 16 + (lane & 15);
        #pragma unroll
        for (int r = 0; r < 4; ++r) {
            int r0 = mb + rb + r, r1 = mb + 16 + rb + r;
            C[(size_t)r0 * 128 + col] = (_Float16)(acc[n][0][r] * scale[r0]);
            C[(size_t)r1 * 128 + col] = (_Float16)(acc[n][1][r] * scale[r1]);
        }
    }
}

// ---------------------------------------------------------------------------
// GCN gather (pair-fused via grid.y), wave-per-node, 4 edges/iteration:
// quarter-wave per edge, 8 ch/lane (half8 16B loads). xwn pre-normalized.
// ---------------------------------------------------------------------------
__global__ __launch_bounds__(256) void gcn_gather2_kernel(
    const int* __restrict__ ssrc0, const int* __restrict__ ssrc1,
    const int* __restrict__ offs0, const int* __restrict__ offs1,
    const float* __restrict__ dinv0, const float* __restrict__ dinv1,
    const _Float16* __restrict__ xwn0, const _Float16* __restrict__ xwn1,
    const float* __restrict__ b0, const float* __restrict__ b1v,
    _Float16* __restrict__ h2)
{
    const int L = blockIdx.y;
    const int* ssrc = L ? ssrc1 : ssrc0;
    const int* offs = L ? offs1 : offs0;
    const float* dinv = L ? dinv1 : dinv0;
    const _Float16* xwn = L ? xwn1 : xwn0;
    const float* b = L ? b1v : b0;
    const int co = L * 128;

    const int t = threadIdx.x;
    const int lane = t & 63;
    const int qg = lane >> 4;
    const int lq = lane & 15;
    const int i = blockIdx.x * 4 + (t >> 6);
    const int e0 = offs[i], e1 = offs[i + 1];
    const float di = dinv[i];

    float ax[8];
    {
        half8 xi = *(const half8*)&xwn[(size_t)i * 128 + lq * 8];
        #pragma unroll
        for (int k = 0; k < 8; ++k) ax[k] = (qg == 0) ? (float)xi[k] : 0.f;
    }

    for (int base = e0; base < e1; base += 64) {
        int k = base + lane;
        int s = 0;
        if (k < e1) s = ssrc[k];
        int m = min(64, e1 - base);
        for (int j = 0; j < m; j += 4) {
            int idx = j + qg;
            int sj = __shfl(s, idx);
            if (idx < m) {
                half8 v = *(const half8*)&xwn[(size_t)sj * 128 + lq * 8];
                #pragma unroll
                for (int k2 = 0; k2 < 8; ++k2) ax[k2] += (float)v[k2];
            }
        }
    }

    #pragma unroll
    for (int k = 0; k < 8; ++k) {
        ax[k] += __shfl(ax[k], lane ^ 16);
        ax[k] += __shfl(ax[k], lane ^ 32);
    }

    if (qg == 0) {
        half8 o;
        #pragma unroll
        for (int k = 0; k < 8; ++k)
            o[k] = (_Float16)fmaxf(ax[k] * di + b[lq * 8 + k], 0.f);
        *(half8*)&h2[(size_t)i * 256 + co + lq * 8] = o;
    }
}

// ---------------------------------------------------------------------------
// c3 GEMM fused with classifier partial reduction, widened to 128 cols per
// block. NO atomics on d_out: each block writes its 3 partials to cpart.
// ---------------------------------------------------------------------------
__global__ __launch_bounds__(256) void gemm_c3cls_kernel(
    const _Float16* __restrict__ A, const _Float16* __restrict__ Bf,
    const float* __restrict__ bias,
    const float* __restrict__ clsW,
    float* __restrict__ cpart)
{
    const int KSTEPS = 8;
    const int t = threadIdx.x;
    const int lane = t & 63;
    const int wv = t >> 6;
    const int mb = blockIdx.x * 32;
    const int ntb = wv * 2;
    const int K = 256;

    const size_t arow0 = (size_t)(mb + (lane & 15)) * K + (lane >> 4) * 8;
    const size_t arow1 = arow0 + (size_t)16 * K;

    floatx4 acc[2][2];
    #pragma unroll
    for (int n = 0; n < 2; ++n)
        #pragma unroll
        for (int r = 0; r < 2; ++r) acc[n][r] = (floatx4){0.f, 0.f, 0.f, 0.f};

    #pragma unroll
    for (int ks = 0; ks < KSTEPS; ++ks) {
        half8 a0 = *(const half8*)&A[arow0 + ks * 32];
        half8 a1 = *(const half8*)&A[arow1 + ks * 32];
        half8 b0 = *(const half8*)&Bf[(size_t)(((ntb + 0) * KSTEPS + ks) * 64 + lane) * 8];
        half8 b1 = *(const half8*)&Bf[(size_t)(((ntb + 1) * KSTEPS + ks) * 64 + lane) * 8];
        acc[0][0] = __builtin_amdgcn_mfma_f32_16x16x32_f16(a0, b0, acc[0][0], 0, 0, 0);
        acc[0][1] = __builtin_amdgcn_mfma_f32_16x16x32_f16(a1, b0, acc[0][1], 0, 0, 0);
        acc[1][0] = __builtin_amdgcn_mfma_f32_16x16x32_f16(a0, b1, acc[1][0], 0, 0, 0);
        acc[1][1] = __builtin_amdgcn_mfma_f32_16x16x32_f16(a1, b1, acc[1][1], 0, 0, 0);
    }

    const int rb = (lane >> 4) * 4;
    float a0 = 0.f, a1 = 0.f, a2 = 0.f;
    #pragma unroll
    for (int n = 0; n < 2; ++n) {
        const int col = (ntb + n) * 16 + (lane & 15);
        const float bb = bias[col];
        #pragma unroll
        for (int r = 0; r < 4; ++r) {
            int r0 = mb + rb + r, r1 = mb + 16 + rb + r;
            float z0 = fmaxf(acc[n][0][r] + bb, 0.f);
            float z1 = fmaxf(acc[n][1][r] + bb, 0.f);
            size_t f0 = ((size_t)r0 * 128 + col) * 3;
            size_t f1 = ((size_t)r1 * 128 + col) * 3;
            a0 += z0 * clsW[f0 + 0] + z1 * clsW[f1 + 0];
            a1 += z0 * clsW[f0 + 1] + z1 * clsW[f1 + 1];
            a2 += z0 * clsW[f0 + 2] + z1 * clsW[f1 + 2];
        }
    }

    #pragma unroll
    for (int off = 32; off > 0; off >>= 1) {
        a0 += __shfl_down(a0, off);
        a1 += __shfl_down(a1, off);
        a2 += __shfl_down(a2, off);
    }
    __shared__ float sred[12];
    if ((t & 63) == 0) { sred[wv * 3] = a0; sred[wv * 3 + 1] = a1; sred[wv * 3 + 2] = a2; }
    __syncthreads();
    if (t == 0) {
        float r0 = 0.f, r1 = 0.f, r2 = 0.f;
        #pragma unroll
        for (int q = 0; q < 4; ++q) { r0 += sred[q * 3]; r1 += sred[q * 3 + 1]; r2 += sred[q * 3 + 2]; }
        cpart[blockIdx.x * 3 + 0] = r0;
        cpart[blockIdx.x * 3 + 1] = r1;
        cpart[blockIdx.x * 3 + 2] = r2;
    }
}

// ---------------------------------------------------------------------------
// Deterministic final reduce: 1 block; wave c sums cpart[:,c] in a fixed
// order (strided serial + fixed shfl tree) -> out[c] = sum + clsb[c].
// Bitwise-identical across launches (no atomics, no schedule dependence).
// ---------------------------------------------------------------------------
__global__ __launch_bounds__(256) void cls_reduce_kernel(
    const float* __restrict__ cpart, const float* __restrict__ clsb,
    float* __restrict__ out)
{
    const int t = threadIdx.x;
    const int c = t >> 6;          // wave -> channel (waves 0..2; wave 3 idle)
    const int lane = t & 63;
    if (c >= 3) return;
    float a = 0.f;
    for (int q = lane; q < NMB; q += 64) a += cpart[q * 3 + c];
    #pragma unroll
    for (int off = 32; off > 0; off >>= 1) a += __shfl_down(a, off);
    if (lane == 0) out[c] = a + clsb[c];
}

// ---------------------------------------------------------------------------
extern "C" void kernel_launch(void* const* d_in, const int* in_sizes, int n_in,
                              void* d_out, int out_size, void* d_ws, size_t ws_size,
                              hipStream_t stream) {
    const float* pos0 = (const float*)d_in[0];
    const float* pos1 = (const float*)d_in[1];
    const int*   ei0  = (const int*)d_in[2];
    const int*   ei1  = (const int*)d_in[3];
    const float* p0W1 = (const float*)d_in[6];
    const float* p0b1 = (const float*)d_in[7];
    const float* p0W2 = (const float*)d_in[8];
    const float* p0b2 = (const float*)d_in[9];
    const float* p1W1 = (const float*)d_in[10];
    const float* p1b1 = (const float*)d_in[11];
    const float* p1W2 = (const float*)d_in[12];
    const float* p1b2 = (const float*)d_in[13];
    const float* g0W  = (const float*)d_in[14];
    const float* g0b  = (const float*)d_in[15];
    const float* g1W  = (const float*)d_in[16];
    const float* g1b  = (const float*)d_in[17];
    const float* c3W  = (const float*)d_in[18];
    const float* c3b  = (const float*)d_in[19];
    const float* clsW = (const float*)d_in[20];
    const float* clsb = (const float*)d_in[21];

    const int* s0 = ei0;       const int* d0 = ei0 + NE;
    const int* s1 = ei1;       const int* d1 = ei1 + NE;

    float* ws = (float*)d_ws;
    _Float16* h   = (_Float16*)ws;               // [N,512] fp16
    _Float16* xw0 = (_Float16*)(ws + 5120000);   // [N,128] fp16 (pre-normalized)
    _Float16* xw1 = (_Float16*)(ws + 7680000);
    _Float16* h2  = (_Float16*)(ws + 10240000);  // [N,256] fp16
    int*   cnt0  = (int*)(ws + 15360000);        // [N]
    int*   cnt1  = (int*)(ws + 15380000);
    int*   cur0  = (int*)(ws + 15400000);
    int*   cur1  = (int*)(ws + 15420000);
    int*   offs0 = (int*)(ws + 15440000);        // [N+1]
    int*   offs1 = (int*)(ws + 15460004);        // [N+1]
    int*   ssrc0 = (int*)(ws + 15480008);        // [E] src payload, dst-sorted
    int*   ssrc1 = (int*)(ws + 15880008);
    float* dinv0 = ws + 16280008;                // [N]
    float* dinv1 = ws + 16300008;
    _Float16* w2f0 = (_Float16*)(ws + 16320008); // 65536 halfs
    _Float16* w2f1 = (_Float16*)(ws + 16352776);
    _Float16* gwf0 = (_Float16*)(ws + 16385544); // 65536 halfs
    _Float16* gwf1 = (_Float16*)(ws + 16418312);
    _Float16* c3f  = (_Float16*)(ws + 16451080); // 32768 halfs
    _Float16* uvb0 = (_Float16*)(ws + 16467464); // 1792 halfs each
    _Float16* uvb1 = (_Float16*)(ws + 16468488);
    float* cpart   = ws + 16469512;              // [NMB*3] classifier partials

    hipMemsetAsync(cnt0, 0, (size_t)2 * N_NODES * sizeof(int), stream);

    // fused histogram + weight fragment / uvb conversions
    const int NCB = (NE + 255) / 256;
    count_wfrag_kernel<<<NCB + 146, 256, 0, stream>>>(
        d0, cnt0, d1, cnt1, p0W2, p1W2, g0W, g1W, c3W,
        p0W1, p1W1, p0b1, p1b1,
        w2f0, w2f1, gwf0, gwf1, c3f, uvb0, uvb1);
    scan2_kernel<<<2, 256, 0, stream>>>(cnt0, offs0, cur0, dinv0,
                                        cnt1, offs1, cur1, dinv1, N_NODES);
    scatter_kernel<<<(NE + 255) / 256, 256, 0, stream>>>(
        s0, d0, cur0, ssrc0, s1, d1, cur1, ssrc1);

    // PointNet, both layers in one dispatch -> h [N,512] fp16
    pointnet_fused_kernel<<<dim3(N_NODES / 8, 2), 256, 0, stream>>>(
        pos0, pos1, ssrc0, ssrc1, offs0, offs1,
        uvb0, uvb1, w2f0, w2f1, p0b2, p1b2, h);

    // xwn pair = (h @ gW) * dinv[row] (fp16 MFMA, K=512) -> fp16
    gemm_mfma2_kernel<16><<<dim3(N_NODES / 32, 1, 2), 256, 0, stream>>>(
        h, gwf0, gwf1, dinv0, dinv1, xw0, xw1);

    // fused GCN aggregation pair (pure segment-sum, 4 edges/iter) -> h2 fp16
    gcn_gather2_kernel<<<dim3(N_NODES / 4, 2), 256, 0, stream>>>(
        ssrc0, ssrc1, offs0, offs1, dinv0, dinv1, xw0, xw1, g0b, g1b, h2);

    // z = relu(h2 @ c3W + c3b) fused with classifier partials (no atomics)
    gemm_c3cls_kernel<<<NMB, 256, 0, stream>>>(h2, c3f, c3b, clsW, cpart);

    // deterministic final reduce -> out[3]
    cls_reduce_kernel<<<1, 256, 0, stream>>>(cpart, clsb, (float*)d_out);
}